// Round 1
// baseline (379.237 us; speedup 1.0000x reference)
//
#include <hip/hip_runtime.h>
#include <hip/hip_bf16.h>
#include <stdint.h>

// Problem constants
#define B_    16
#define N_    577
#define C_    768
#define H_    12
#define DH_   64
#define M_    (B_*N_)     // 9232 rows
#define QKVN  (3*C_)      // 2304
#define NKEEP 403         // int(576*0.7)
#define KROWS (NKEEP+1)   // 404

typedef short s16x8 __attribute__((ext_vector_type(8)));
typedef float f32x4 __attribute__((ext_vector_type(4)));

__device__ __forceinline__ unsigned short f2bf(float x){
  unsigned int u = __float_as_uint(x);
  u += 0x7FFF + ((u >> 16) & 1);          // round-to-nearest-even
  return (unsigned short)(u >> 16);
}

// ---------------- cast x -> bf16 (vectorized) ----------------
__global__ void k_cvt_x(const float* __restrict__ x, unsigned short* __restrict__ xb){
  int i = blockIdx.x*256 + threadIdx.x;   // one float4 per thread
  float4 v = ((const float4*)x)[i];
  ushort4 o; o.x=f2bf(v.x); o.y=f2bf(v.y); o.z=f2bf(v.z); o.w=f2bf(v.w);
  ((ushort4*)xb)[i] = o;
}

// ------------- transpose+cast weights: out[c][r] = bf16(in[r][c]) -------------
// in: R x CC f32, out: CC x R bf16. grid (CC/64, R/64), 256 threads.
__global__ void k_transpose_cvt(const float* __restrict__ in, unsigned short* __restrict__ out,
                                int R, int CC){
  __shared__ float tile[64][65];
  int r0 = blockIdx.y*64, c0 = blockIdx.x*64;
  int tx = threadIdx.x & 63, ty = threadIdx.x >> 6;
  #pragma unroll
  for(int i=0;i<16;i++){
    int r = ty + i*4;
    tile[r][tx] = in[(size_t)(r0+r)*CC + c0 + tx];
  }
  __syncthreads();
  #pragma unroll
  for(int i=0;i<16;i++){
    int c = ty + i*4;   // which col of the input tile -> output row
    out[(size_t)(c0+c)*R + r0 + tx] = f2bf(tile[tx][c]);
  }
}

// ---------------- bf16 MFMA GEMM, Bt layout: C[m][n] = sum_k A[m][k]*Bt[n][k] ----------------
// A: Mdim x 768, Bt: N x 768 (both bf16), K=768. 128x128 tile, BK=32, 4 waves of 64x64.
template<int LDC_, bool BF16OUT>
__global__ void k_gemm_bt(const unsigned short* __restrict__ A,
                          const unsigned short* __restrict__ Bt,
                          void* __restrict__ Cout,
                          const float* __restrict__ bias, int Mdim){
  __shared__ unsigned short As[128*40];   // +8 pad: 80B row stride -> conflict-free b128
  __shared__ unsigned short Bs[128*40];
  const int t = threadIdx.x;
  const int w = t>>6, l = t&63, lq = l>>4, lr = l&15;
  const int wm = w>>1, wn = w&1;
  const int m0 = blockIdx.x*128, n0 = blockIdx.y*128;
  f32x4 acc[4][4] = {};
  for(int kt=0; kt<24; ++kt){
    const int k0 = kt*32;
    __syncthreads();
    #pragma unroll
    for(int c=0;c<2;c++){
      int chunk = t + c*256;               // 512 chunks each of 8 bf16
      int row = chunk>>2, ko = (chunk&3)*8;
      int rowA = m0+row; if(rowA >= Mdim) rowA = Mdim-1;
      *(uint4*)&As[row*40 + ko] = *(const uint4*)&A[(size_t)rowA*768 + k0 + ko];
      *(uint4*)&Bs[row*40 + ko] = *(const uint4*)&Bt[(size_t)(n0+row)*768 + k0 + ko];
    }
    __syncthreads();
    s16x8 af[4], bfr[4];
    #pragma unroll
    for(int it=0;it<4;it++) af[it]  = *(const s16x8*)&As[(wm*64+it*16+lr)*40 + lq*8];
    #pragma unroll
    for(int jt=0;jt<4;jt++) bfr[jt] = *(const s16x8*)&Bs[(wn*64+jt*16+lr)*40 + lq*8];
    #pragma unroll
    for(int it=0;it<4;it++)
      #pragma unroll
      for(int jt=0;jt<4;jt++)
        acc[it][jt] = __builtin_amdgcn_mfma_f32_16x16x32_bf16(af[it], bfr[jt], acc[it][jt], 0,0,0);
  }
  // epilogue: C/D layout col=lane&15, row=(lane>>4)*4+reg
  #pragma unroll
  for(int it=0;it<4;it++){
    #pragma unroll
    for(int r=0;r<4;r++){
      int row = m0 + wm*64 + it*16 + lq*4 + r;
      if(row < Mdim){
        #pragma unroll
        for(int jt=0;jt<4;jt++){
          int col = n0 + wn*64 + jt*16 + lr;
          float v = acc[it][jt][r];
          if constexpr (BF16OUT)
            ((unsigned short*)Cout)[(size_t)row*LDC_ + col] = f2bf(v);
          else
            ((float*)Cout)[(size_t)row*LDC_ + col] = v + bias[col];
        }
      }
    }
  }
}

// ---------------- fused flash attention per (b, h, q-tile of 64) ----------------
// qkv layout: [(b*577+n)*2304 + which*768 + h*64 + d], bf16. aout: [(b*577+n)*768 + h*64+d] bf16.
__global__ __launch_bounds__(256) void k_attn(const unsigned short* __restrict__ qkv,
                                              unsigned short* __restrict__ aout){
  __shared__ unsigned short Qs[64*72];     //  9216 B
  __shared__ unsigned short Ks[128*72];    // 18432 B
  __shared__ unsigned short Vt[64*136];    // 17408 B (transposed V: [d][j])
  __shared__ unsigned short Ps[64*136];    // 17408 B (per-wave 16-row regions)
  const int blk = blockIdx.x;
  const int qt = blk % 10, h = (blk/10) % 12, b = blk/120;
  const int t = threadIdx.x, w = t>>6, l = t&63, lq = l>>4, lr = l&15;
  const size_t base = (size_t)(b*577)*2304 + h*64;
  // stage Q tile (64 rows x 64 cols)
  #pragma unroll
  for(int i=0;i<2;i++){
    int task = t + i*256;
    int row = task>>3, ck = task&7;
    int n = qt*64 + row; if(n > 576) n = 576;
    *(uint4*)&Qs[row*72 + ck*8] = *(const uint4*)&qkv[base + (size_t)n*2304 + ck*8];
  }
  f32x4 acc_o[4] = {};
  float mrow[4] = {-1e30f,-1e30f,-1e30f,-1e30f};
  float lrow[4] = {0.f,0.f,0.f,0.f};
  for(int j0=0; j0<577; j0+=128){
    __syncthreads();
    // stage K tile (128 x 64) as Bt
    #pragma unroll
    for(int i=0;i<4;i++){
      int task = t + i*256;
      int row = task>>3, ck = task&7;
      int n = j0 + row; if(n > 576) n = 576;
      *(uint4*)&Ks[row*72 + ck*8] = *(const uint4*)&qkv[base + 768 + (size_t)n*2304 + ck*8];
    }
    // stage V transposed: Vt[d][j]
    #pragma unroll
    for(int i=0;i<32;i++){
      int task = t + i*256;
      int jj = task>>6, d = task&63;
      int n = j0 + jj; if(n > 576) n = 576;
      Vt[d*136 + jj] = qkv[base + 1536 + (size_t)n*2304 + d];
    }
    __syncthreads();
    // S = Q @ K^T : wave w owns rows w*16..+15, all 128 cols
    f32x4 accs[8] = {};
    #pragma unroll
    for(int ks=0;ks<2;ks++){
      s16x8 aq = *(const s16x8*)&Qs[(w*16+lr)*72 + ks*32 + lq*8];
      #pragma unroll
      for(int jt=0;jt<8;jt++){
        s16x8 bk = *(const s16x8*)&Ks[(jt*16+lr)*72 + ks*32 + lq*8];
        accs[jt] = __builtin_amdgcn_mfma_f32_16x16x32_bf16(aq, bk, accs[jt], 0,0,0);
      }
    }
    // online softmax, per owned row r (C-layout: row=(l>>4)*4+r, col=lane&15)
    #pragma unroll
    for(int r=0;r<4;r++){
      float sv[8]; float rmax = -1e30f;
      #pragma unroll
      for(int jt=0;jt<8;jt++){
        int j = j0 + jt*16 + lr;
        float s = accs[jt][r] * 0.125f;
        if(j > 576) s = -1e30f;
        sv[jt] = s; rmax = fmaxf(rmax, s);
      }
      #pragma unroll
      for(int off=1; off<16; off<<=1) rmax = fmaxf(rmax, __shfl_xor(rmax, off));
      float mnew = fmaxf(mrow[r], rmax);
      float alpha = __expf(mrow[r] - mnew);
      float rsum = 0.f;
      #pragma unroll
      for(int jt=0;jt<8;jt++){
        float p = __expf(sv[jt] - mnew);
        rsum += p;
        Ps[(w*16 + lq*4 + r)*136 + jt*16 + lr] = f2bf(p);
      }
      #pragma unroll
      for(int off=1; off<16; off<<=1) rsum += __shfl_xor(rsum, off);
      lrow[r] = lrow[r]*alpha + rsum;
      mrow[r] = mnew;
      acc_o[0][r]*=alpha; acc_o[1][r]*=alpha; acc_o[2][r]*=alpha; acc_o[3][r]*=alpha;
    }
    __syncthreads();   // P LDS writes -> A-frag reads
    // O += P @ V  (A = P rows, Bt = Vt)
    #pragma unroll
    for(int ks=0;ks<4;ks++){
      s16x8 ap = *(const s16x8*)&Ps[(w*16+lr)*136 + ks*32 + lq*8];
      #pragma unroll
      for(int dt=0;dt<4;dt++){
        s16x8 bv = *(const s16x8*)&Vt[(dt*16+lr)*136 + ks*32 + lq*8];
        acc_o[dt] = __builtin_amdgcn_mfma_f32_16x16x32_bf16(ap, bv, acc_o[dt], 0,0,0);
      }
    }
  }
  #pragma unroll
  for(int r=0;r<4;r++){
    int n = qt*64 + w*16 + lq*4 + r;
    if(n <= 576){
      float inv = 1.f / lrow[r];
      #pragma unroll
      for(int dt=0;dt<4;dt++)
        aout[(size_t)(b*577+n)*768 + h*64 + dt*16 + lr] = f2bf(acc_o[dt][r]*inv);
    }
  }
}

// ---------------- fp32 top-k path ----------------
// q_cls[b][j] = sum_c x[b,0,c] * Wqkv[c][j]   (j = h*64+d in the Q block)
__global__ void k_qcls(const float* __restrict__ x, const float* __restrict__ Wqkv,
                       float* __restrict__ qcls){
  int b = blockIdx.x, j = threadIdx.x;   // 768 threads
  const float* xr = x + (size_t)b*577*768;
  float acc = 0.f;
  for(int c=0;c<768;c++) acc += xr[c] * Wqkv[(size_t)c*2304 + j];
  qcls[b*768 + j] = acc;
}
// u[b][h][c] = sum_d Wqkv[c][768 + h*64 + d] * q_cls[b][h*64+d]
__global__ void k_u(const float* __restrict__ Wqkv, const float* __restrict__ qcls,
                    float* __restrict__ u){
  int h = blockIdx.x, b = blockIdx.y, c = threadIdx.x;  // 768 threads
  const float* qc = qcls + b*768 + h*64;
  const float* wr = Wqkv + (size_t)c*2304 + 768 + h*64;
  float acc = 0.f;
  #pragma unroll
  for(int d=0;d<64;d++) acc += wr[d]*qc[d];
  u[(size_t)(b*12+h)*768 + c] = acc;
}
// attw[b][m] = 0.125 * sum_h | x[b,m,:] . u[b,h,:] |
__global__ void k_attw(const float* __restrict__ x, const float* __restrict__ u,
                       float* __restrict__ attw){
  int blk = blockIdx.x;               // 16*577 blocks of 1 wave
  int b = blk/577, m = blk%577;
  int lane = threadIdx.x;
  const float* xr = x + (size_t)(b*577+m)*768;
  const float* ub = u + (size_t)b*12*768;
  float part[12];
  #pragma unroll
  for(int h=0;h<12;h++) part[h]=0.f;
  #pragma unroll
  for(int i=0;i<12;i++){
    float xv = xr[i*64 + lane];
    #pragma unroll
    for(int h=0;h<12;h++) part[h] += xv * ub[h*768 + i*64 + lane];
  }
  float s = 0.f;
  #pragma unroll
  for(int h=0;h<12;h++){
    float v = part[h];
    #pragma unroll
    for(int off=32; off; off>>=1) v += __shfl_xor(v, off);
    s += fabsf(v);
  }
  if(lane==0) attw[b*577 + m] = 0.125f * s;
}
// per-batch top-403 by rank + index-ordered compaction (stable tie-break = lower index wins)
__global__ void k_topk(const float* __restrict__ attw, int* __restrict__ idxbuf){
  __shared__ float sw[576];
  __shared__ int wtot[9];
  int b = blockIdx.x, t = threadIdx.x;     // 576 threads
  float wv = attw[b*577 + 1 + t];
  sw[t] = wv;
  __syncthreads();
  int rank = 0;
  for(int j=0;j<576;j++){
    float wj = sw[j];
    rank += (wj > wv) || (wj == wv && j < t);
  }
  bool kept = rank < NKEEP;
  unsigned long long mask = __ballot(kept);
  int wid = t>>6, lane = t&63;
  int pos = __popcll(mask & ((1ull<<lane)-1ull));
  if(lane==0) wtot[wid] = __popcll(mask);
  __syncthreads();
  int off0 = 0;
  for(int q=0;q<wid;q++) off0 += wtot[q];
  if(kept) idxbuf[b*KROWS + 1 + off0 + pos] = t+1;
  if(t==0) idxbuf[b*KROWS] = 0;
}
__global__ void k_fill_keep(const int* __restrict__ idxbuf, float* __restrict__ out2){
  int i = blockIdx.x*256 + threadIdx.x;    // 16*404*768 elems, exact grid
  out2[i] = (float)idxbuf[i/768];          // i/768 == b*404 + j
}

extern "C" void kernel_launch(void* const* d_in, const int* in_sizes, int n_in,
                              void* d_out, int out_size, void* d_ws, size_t ws_size,
                              hipStream_t stream){
  const float* x     = (const float*)d_in[0];
  const float* Wqkv  = (const float*)d_in[1];
  const float* Wproj = (const float*)d_in[2];
  const float* bias  = (const float*)d_in[3];
  float* out  = (float*)d_out;
  float* out2 = out + (size_t)M_*768;      // keep_index chunk (float32)

  char* ws = (char*)d_ws;
  size_t off = 0;
  auto alloc = [&](size_t bytes)->void*{ void* p = ws + off; off += (bytes + 255) & ~(size_t)255; return p; };
  unsigned short* xb     = (unsigned short*)alloc((size_t)M_*768*2);
  unsigned short* wqkvT  = (unsigned short*)alloc((size_t)QKVN*768*2);
  unsigned short* wprojT = (unsigned short*)alloc((size_t)768*768*2);
  unsigned short* qkvb   = (unsigned short*)alloc((size_t)M_*QKVN*2);
  unsigned short* aoutb  = (unsigned short*)alloc((size_t)M_*768*2);
  float* qcls   = (float*)alloc((size_t)16*768*4);
  float* u      = (float*)alloc((size_t)16*12*768*4);
  float* attw   = (float*)alloc((size_t)16*577*4);
  int*   idxbuf = (int*)alloc((size_t)16*KROWS*4);

  // bf16 casts / transposes
  k_cvt_x<<<6924, 256, 0, stream>>>(x, xb);                                   // 9232*768/4
  k_transpose_cvt<<<dim3(36,12), 256, 0, stream>>>(Wqkv,  wqkvT, 768, 2304);
  k_transpose_cvt<<<dim3(12,12), 256, 0, stream>>>(Wproj, wprojT, 768, 768);
  // QKV GEMM (bf16 out)
  k_gemm_bt<QKVN, true><<<dim3(73,18), 256, 0, stream>>>(xb, wqkvT, qkvb, nullptr, M_);
  // fp32 top-k weight path (exact ranking)
  k_qcls<<<16, 768, 0, stream>>>(x, Wqkv, qcls);
  k_u<<<dim3(12,16), 768, 0, stream>>>(Wqkv, qcls, u);
  k_attw<<<16*577, 64, 0, stream>>>(x, u, attw);
  k_topk<<<16, 576, 0, stream>>>(attw, idxbuf);
  k_fill_keep<<<(16*KROWS*768)/256, 256, 0, stream>>>(idxbuf, out2);
  // attention + out-proj
  k_attn<<<16*12*10, 256, 0, stream>>>(qkvb, aoutb);
  k_gemm_bt<768, false><<<dim3(73,6), 256, 0, stream>>>(aoutb, wprojT, out, bias, M_);
}